// Round 1
// baseline (1449.642 us; speedup 1.0000x reference)
//
#include <hip/hip_runtime.h>
#include <cstdint>

#define N_NODES 50000
#define N_EDGES 800000
#define E_TOT   (N_EDGES + N_NODES)   // 850000 with self-loops
#define IN_CH   128
#define HEADS   8
#define CCH     32
#define HC      256                    // HEADS*CCH
#define OUTC    64

// ---------------- Layer 1 GEMM: h1 = x @ W1  ([N,128]@[128,256]) -----------
// block = 256 threads (one per output col), tile of 8 nodes per block.
__global__ __launch_bounds__(256) void gemm1_kernel(
        const float* __restrict__ x, const float* __restrict__ W1,
        float* __restrict__ h1) {
    __shared__ float xs[8][IN_CH];
    const int j  = threadIdx.x;            // output column 0..255
    const int n0 = blockIdx.x * 8;
    for (int i = threadIdx.x; i < 8 * IN_CH; i += 256) {
        int m = i >> 7, k = i & (IN_CH - 1);
        xs[m][k] = x[(size_t)(n0 + m) * IN_CH + k];   // N%8==0, always valid
    }
    __syncthreads();
    float acc[8] = {0.f,0.f,0.f,0.f,0.f,0.f,0.f,0.f};
    for (int k = 0; k < IN_CH; ++k) {
        float w = W1[k * HC + j];
        #pragma unroll
        for (int m = 0; m < 8; ++m) acc[m] += xs[m][k] * w;
    }
    #pragma unroll
    for (int m = 0; m < 8; ++m)
        h1[(size_t)(n0 + m) * HC + j] = acc[m];
}

// ------------- Layer 1 attention logits: al/ar [N,8] ------------------------
__global__ __launch_bounds__(256) void attn_logits1(
        const float* __restrict__ h1, const float* __restrict__ a_src,
        const float* __restrict__ a_dst, float* __restrict__ al,
        float* __restrict__ ar) {
    const int n = blockIdx.x;
    const int j = threadIdx.x;             // h = j>>5, c = j&31
    float v = h1[(size_t)n * HC + j];
    float s = v * a_src[j];
    float d = v * a_dst[j];
    #pragma unroll
    for (int o = 16; o; o >>= 1) {
        s += __shfl_down(s, o, 32);
        d += __shfl_down(d, o, 32);
    }
    if ((j & 31) == 0) {
        al[n * HEADS + (j >> 5)] = s;
        ar[n * HEADS + (j >> 5)] = d;
    }
}

// ---------- Edge pass A (layer 1): softmax denominators  s1[N,8] ------------
__global__ __launch_bounds__(256) void edge_denom1(
        const int* __restrict__ ei, const float* __restrict__ al,
        const float* __restrict__ ar, float* __restrict__ s1) {
    int e = blockIdx.x * 256 + threadIdx.x;
    if (e >= E_TOT) return;
    int sv, dv;
    if (e < N_EDGES) { sv = ei[e]; dv = ei[N_EDGES + e]; }
    else             { sv = dv = e - N_EDGES; }
    #pragma unroll
    for (int h = 0; h < HEADS; ++h) {
        float eh = al[sv * HEADS + h] + ar[dv * HEADS + h];
        eh = eh > 0.f ? eh : 0.2f * eh;            // LeakyReLU(0.2)
        atomicAdd(&s1[dv * HEADS + h], expf(eh));  // no max-shift: softmax invariant
    }
}

// ---------- Edge pass B (layer 1): out1[dst] += alpha * h1[src] -------------
// block = 256 threads (one per channel), 4 edges per block.
__global__ __launch_bounds__(256) void edge_aggr1(
        const int* __restrict__ ei, const float* __restrict__ al,
        const float* __restrict__ ar, const float* __restrict__ s1,
        const float* __restrict__ h1, float* __restrict__ out1) {
    const int t = threadIdx.x;
    const int h = t >> 5;
    const int e0 = blockIdx.x * 4;
    #pragma unroll
    for (int q = 0; q < 4; ++q) {
        int e = e0 + q;
        if (e >= E_TOT) return;                    // uniform across block
        int sv, dv;
        if (e < N_EDGES) { sv = ei[e]; dv = ei[N_EDGES + e]; }
        else             { sv = dv = e - N_EDGES; }
        float eh = al[sv * HEADS + h] + ar[dv * HEADS + h];
        eh = eh > 0.f ? eh : 0.2f * eh;
        float alpha = expf(eh) / (s1[dv * HEADS + h] + 1e-16f);
        atomicAdd(&out1[(size_t)dv * HC + t], h1[(size_t)sv * HC + t] * alpha);
    }
}

// --------------- ELU (+b1) in-place on out1 ---------------------------------
__global__ __launch_bounds__(256) void elu1_kernel(
        float* __restrict__ out1, const float* __restrict__ b1) {
    int i = blockIdx.x * 256 + threadIdx.x;
    if (i >= N_NODES * HC) return;
    float v = out1[i] + b1[i & (HC - 1)];
    out1[i] = v > 0.f ? v : expf(v) - 1.f;
}

// ---------------- Layer 2 GEMM: h2 = elu_out @ W2 ([N,256]@[256,64]) --------
// block = 256 threads = 64 cols x 4 node-slots; tile 16 nodes; 4 nodes/thread.
__global__ __launch_bounds__(256) void gemm2_kernel(
        const float* __restrict__ hin, const float* __restrict__ W2,
        float* __restrict__ h2) {
    __shared__ float xs[16][HC];
    const int j    = threadIdx.x & 63;     // output column
    const int msub = threadIdx.x >> 6;     // 0..3
    const int n0   = blockIdx.x * 16;
    for (int i = threadIdx.x; i < 16 * HC; i += 256) {
        int m = i >> 8, k = i & (HC - 1);
        xs[m][k] = hin[(size_t)(n0 + m) * HC + k];  // N%16==0
    }
    __syncthreads();
    float acc[4] = {0.f,0.f,0.f,0.f};
    for (int k = 0; k < HC; ++k) {
        float w = W2[k * OUTC + j];
        #pragma unroll
        for (int r = 0; r < 4; ++r) acc[r] += xs[msub + 4 * r][k] * w;
    }
    #pragma unroll
    for (int r = 0; r < 4; ++r)
        h2[(size_t)(n0 + msub + 4 * r) * OUTC + j] = acc[r];
}

// ------------- Layer 2 attention logits: al2/ar2 [N] ------------------------
__global__ __launch_bounds__(256) void attn_logits2(
        const float* __restrict__ h2, const float* __restrict__ a_src,
        const float* __restrict__ a_dst, float* __restrict__ al,
        float* __restrict__ ar) {
    const int n = blockIdx.x * 4 + (threadIdx.x >> 6);
    const int c = threadIdx.x & 63;
    float v = h2[(size_t)n * OUTC + c];
    float s = v * a_src[c];
    float d = v * a_dst[c];
    #pragma unroll
    for (int o = 32; o; o >>= 1) {
        s += __shfl_down(s, o, 64);
        d += __shfl_down(d, o, 64);
    }
    if (c == 0) { al[n] = s; ar[n] = d; }
}

// ---------- Edge pass A (layer 2) -------------------------------------------
__global__ __launch_bounds__(256) void edge_denom2(
        const int* __restrict__ ei, const float* __restrict__ al,
        const float* __restrict__ ar, float* __restrict__ s2) {
    int e = blockIdx.x * 256 + threadIdx.x;
    if (e >= E_TOT) return;
    int sv, dv;
    if (e < N_EDGES) { sv = ei[e]; dv = ei[N_EDGES + e]; }
    else             { sv = dv = e - N_EDGES; }
    float eh = al[sv] + ar[dv];
    eh = eh > 0.f ? eh : 0.2f * eh;
    atomicAdd(&s2[dv], expf(eh));
}

// ---------- Edge pass B (layer 2): out[dst] += alpha * h2[src] --------------
// block = 256 threads = 4 edges x 64 channels.
__global__ __launch_bounds__(256) void edge_aggr2(
        const int* __restrict__ ei, const float* __restrict__ al,
        const float* __restrict__ ar, const float* __restrict__ s2,
        const float* __restrict__ h2, float* __restrict__ out) {
    const int q = threadIdx.x >> 6;
    const int c = threadIdx.x & 63;
    int e = blockIdx.x * 4 + q;
    if (e >= E_TOT) return;
    int sv, dv;
    if (e < N_EDGES) { sv = ei[e]; dv = ei[N_EDGES + e]; }
    else             { sv = dv = e - N_EDGES; }
    float eh = al[sv] + ar[dv];
    eh = eh > 0.f ? eh : 0.2f * eh;
    float alpha = expf(eh) / (s2[dv] + 1e-16f);
    atomicAdd(&out[(size_t)dv * OUTC + c], h2[(size_t)sv * OUTC + c] * alpha);
}

// --------------- final bias add ---------------------------------------------
__global__ __launch_bounds__(256) void bias2_kernel(
        float* __restrict__ out, const float* __restrict__ b2) {
    int i = blockIdx.x * 256 + threadIdx.x;
    if (i >= N_NODES * OUTC) return;
    out[i] += b2[i & (OUTC - 1)];
}

extern "C" void kernel_launch(void* const* d_in, const int* in_sizes, int n_in,
                              void* d_out, int out_size, void* d_ws, size_t ws_size,
                              hipStream_t stream) {
    const float* x      = (const float*)d_in[0];
    const int*   ei     = (const int*)  d_in[1];   // [2, E] row-major
    const float* W1     = (const float*)d_in[2];
    const float* a_src1 = (const float*)d_in[3];
    const float* a_dst1 = (const float*)d_in[4];
    const float* b1     = (const float*)d_in[5];
    const float* W2     = (const float*)d_in[6];
    const float* a_src2 = (const float*)d_in[7];
    const float* a_dst2 = (const float*)d_in[8];
    const float* b2     = (const float*)d_in[9];
    float* out = (float*)d_out;

    // workspace layout (floats)
    float* ws   = (float*)d_ws;
    float* h1   = ws;                        // N*256
    float* al1  = h1  + (size_t)N_NODES*HC;  // N*8
    float* ar1  = al1 + (size_t)N_NODES*HEADS;
    float* s1   = ar1 + (size_t)N_NODES*HEADS;
    float* out1 = s1  + (size_t)N_NODES*HEADS;   // N*256
    float* h2   = out1+ (size_t)N_NODES*HC;      // N*64
    float* al2  = h2  + (size_t)N_NODES*OUTC;    // N
    float* ar2  = al2 + N_NODES;
    float* s2   = ar2 + N_NODES;

    // zero accumulators (must happen every call: harness doesn't re-poison)
    hipMemsetAsync(s1,   0, (size_t)N_NODES*HEADS*sizeof(float), stream);
    hipMemsetAsync(out1, 0, (size_t)N_NODES*HC*sizeof(float),    stream);
    hipMemsetAsync(s2,   0, (size_t)N_NODES*sizeof(float),       stream);
    hipMemsetAsync(out,  0, (size_t)N_NODES*OUTC*sizeof(float),  stream);

    // ---- layer 1 ----
    gemm1_kernel<<<N_NODES/8, 256, 0, stream>>>(x, W1, h1);
    attn_logits1<<<N_NODES, 256, 0, stream>>>(h1, a_src1, a_dst1, al1, ar1);
    edge_denom1<<<(E_TOT + 255)/256, 256, 0, stream>>>(ei, al1, ar1, s1);
    edge_aggr1<<<(E_TOT + 3)/4, 256, 0, stream>>>(ei, al1, ar1, s1, h1, out1);
    elu1_kernel<<<(N_NODES*HC + 255)/256, 256, 0, stream>>>(out1, b1);

    // ---- layer 2 ----
    gemm2_kernel<<<N_NODES/16, 256, 0, stream>>>(out1, W2, h2);
    attn_logits2<<<N_NODES/4, 256, 0, stream>>>(h2, a_src2, a_dst2, al2, ar2);
    edge_denom2<<<(E_TOT + 255)/256, 256, 0, stream>>>(ei, al2, ar2, s2);
    edge_aggr2<<<(E_TOT + 3)/4, 256, 0, stream>>>(ei, al2, ar2, s2, h2, out);
    bias2_kernel<<<(N_NODES*OUTC + 255)/256, 256, 0, stream>>>(out, b2);
}

// Round 2
// 486.745 us; speedup vs baseline: 2.9782x; 2.9782x over previous
//
#include <hip/hip_runtime.h>
#include <cstdint>

#define N_NODES 50000
#define N_EDGES 800000
#define E_TOT   (N_EDGES + N_NODES)   // 850000 with self-loops
#define IN_CH   128
#define HEADS   8
#define CCH     32
#define HC      256                    // HEADS*CCH
#define OUTC    64

// ======================= CSR construction (per call) ========================
__global__ __launch_bounds__(256) void hist_kernel(
        const int* __restrict__ ei, int* __restrict__ deg) {
    int e = blockIdx.x * 256 + threadIdx.x;
    if (e >= E_TOT) return;
    int dv = (e < N_EDGES) ? ei[N_EDGES + e] : (e - N_EDGES);
    atomicAdd(&deg[dv], 1);
}

// block-level inclusive scan (Hillis-Steele, 1024/block)
__global__ __launch_bounds__(1024) void scan1_kernel(
        const int* __restrict__ deg, int* __restrict__ inc, int* __restrict__ bsum) {
    __shared__ int sh[1024];
    const int tid = threadIdx.x;
    const int i = blockIdx.x * 1024 + tid;
    sh[tid] = (i < N_NODES) ? deg[i] : 0;
    __syncthreads();
    for (int o = 1; o < 1024; o <<= 1) {
        int t = (tid >= o) ? sh[tid - o] : 0;
        __syncthreads();
        sh[tid] += t;
        __syncthreads();
    }
    if (i < N_NODES) inc[i] = sh[tid];
    if (tid == 1023) bsum[blockIdx.x] = sh[1023];
}

#define NSCAN_BLOCKS ((N_NODES + 1023) / 1024)   // 49
__global__ void scan2_kernel(int* __restrict__ bsum) {
    if (threadIdx.x == 0 && blockIdx.x == 0) {
        int acc = 0;
        for (int k = 0; k < NSCAN_BLOCKS; ++k) { int t = bsum[k]; bsum[k] = acc; acc += t; }
    }
}

__global__ __launch_bounds__(256) void finalize_kernel(
        const int* __restrict__ inc, const int* __restrict__ bsum,
        int* __restrict__ rowstart, int* __restrict__ cursor) {
    int i = blockIdx.x * 256 + threadIdx.x;
    if (i >= N_NODES) return;
    int v = inc[i] + bsum[i >> 10];      // global inclusive prefix at i
    rowstart[i + 1] = v;
    if (i + 1 < N_NODES) cursor[i + 1] = v;
    if (i == 0) { rowstart[0] = 0; cursor[0] = 0; }
}

__global__ __launch_bounds__(256) void scatter_kernel(
        const int* __restrict__ ei, int* __restrict__ cursor, int* __restrict__ col) {
    int e = blockIdx.x * 256 + threadIdx.x;
    if (e >= E_TOT) return;
    int sv, dv;
    if (e < N_EDGES) { sv = ei[e]; dv = ei[N_EDGES + e]; }
    else             { sv = dv = e - N_EDGES; }
    int pos = atomicAdd(&cursor[dv], 1);
    col[pos] = sv;
}

// ======================= Layer 1 GEMM: h1 = x @ W1 ==========================
__global__ __launch_bounds__(256) void gemm1_kernel(
        const float* __restrict__ x, const float* __restrict__ W1,
        float* __restrict__ h1) {
    __shared__ float xs[8][IN_CH];
    const int j  = threadIdx.x;
    const int n0 = blockIdx.x * 8;
    for (int i = threadIdx.x; i < 8 * IN_CH; i += 256) {
        int m = i >> 7, k = i & (IN_CH - 1);
        xs[m][k] = x[(size_t)(n0 + m) * IN_CH + k];
    }
    __syncthreads();
    float acc[8] = {0.f,0.f,0.f,0.f,0.f,0.f,0.f,0.f};
    for (int k = 0; k < IN_CH; ++k) {
        float w = W1[k * HC + j];
        #pragma unroll
        for (int m = 0; m < 8; ++m) acc[m] += xs[m][k] * w;
    }
    #pragma unroll
    for (int m = 0; m < 8; ++m)
        h1[(size_t)(n0 + m) * HC + j] = acc[m];
}

// ------------- Layer 1 attention logits: al/ar [N,8] ------------------------
__global__ __launch_bounds__(256) void attn_logits1(
        const float* __restrict__ h1, const float* __restrict__ a_src,
        const float* __restrict__ a_dst, float* __restrict__ al,
        float* __restrict__ ar) {
    const int n = blockIdx.x;
    const int j = threadIdx.x;
    float v = h1[(size_t)n * HC + j];
    float s = v * a_src[j];
    float d = v * a_dst[j];
    #pragma unroll
    for (int o = 16; o; o >>= 1) {
        s += __shfl_down(s, o, 32);
        d += __shfl_down(d, o, 32);
    }
    if ((j & 31) == 0) {
        al[n * HEADS + (j >> 5)] = s;
        ar[n * HEADS + (j >> 5)] = d;
    }
}

// ===== Layer 1 fused: denom + weighted gather + bias + ELU (wave per dst) ===
__global__ __launch_bounds__(256) void aggr1_csr(
        const int* __restrict__ rowstart, const int* __restrict__ col,
        const float* __restrict__ al, const float* __restrict__ ar,
        const float* __restrict__ h1, const float* __restrict__ b1,
        float* __restrict__ out1) {
    const int lane = threadIdx.x & 63;
    const int d = blockIdx.x * 4 + (threadIdx.x >> 6);
    if (d >= N_NODES) return;
    const int beg = rowstart[d], end = rowstart[d + 1];

    // pass 1: softmax denominator. lane handles head hh=lane&7, edge group lane>>3
    const int hh = lane & 7;
    const float ar_hh = ar[d * HEADS + hh];
    float denom = 0.f;
    for (int i = beg + (lane >> 3); i < end; i += 8) {
        int s = col[i];
        float eh = al[s * HEADS + hh] + ar_hh;
        eh = eh > 0.f ? eh : 0.2f * eh;
        denom += expf(eh);
    }
    denom += __shfl_xor(denom, 8, 64);
    denom += __shfl_xor(denom, 16, 64);
    denom += __shfl_xor(denom, 32, 64);          // every lane: denom of head lane&7
    const int h = lane >> 3;                     // head of my 4 channels
    const float mydenom = __shfl(denom, h, 64) + 1e-16f;  // lane h holds head h's denom

    // pass 2: weighted accumulation of h1[src]
    const float ar_h = ar[d * HEADS + h];
    float4 acc = {0.f, 0.f, 0.f, 0.f};
    for (int i = beg; i < end; ++i) {
        int s = col[i];
        float eh = al[s * HEADS + h] + ar_h;
        eh = eh > 0.f ? eh : 0.2f * eh;
        float w = expf(eh) / mydenom;
        const float4 hv = *(const float4*)&h1[(size_t)s * HC + 4 * lane];
        acc.x += w * hv.x; acc.y += w * hv.y; acc.z += w * hv.z; acc.w += w * hv.w;
    }
    // bias + ELU fused
    const float4 bb = *(const float4*)&b1[4 * lane];
    acc.x += bb.x; acc.y += bb.y; acc.z += bb.z; acc.w += bb.w;
    acc.x = acc.x > 0.f ? acc.x : expf(acc.x) - 1.f;
    acc.y = acc.y > 0.f ? acc.y : expf(acc.y) - 1.f;
    acc.z = acc.z > 0.f ? acc.z : expf(acc.z) - 1.f;
    acc.w = acc.w > 0.f ? acc.w : expf(acc.w) - 1.f;
    *(float4*)&out1[(size_t)d * HC + 4 * lane] = acc;
}

// ======================= Layer 2 GEMM: h2 = out1 @ W2 =======================
__global__ __launch_bounds__(256) void gemm2_kernel(
        const float* __restrict__ hin, const float* __restrict__ W2,
        float* __restrict__ h2) {
    __shared__ float xs[16][HC];
    const int j    = threadIdx.x & 63;
    const int msub = threadIdx.x >> 6;
    const int n0   = blockIdx.x * 16;
    for (int i = threadIdx.x; i < 16 * HC; i += 256) {
        int m = i >> 8, k = i & (HC - 1);
        xs[m][k] = hin[(size_t)(n0 + m) * HC + k];
    }
    __syncthreads();
    float acc[4] = {0.f,0.f,0.f,0.f};
    for (int k = 0; k < HC; ++k) {
        float w = W2[k * OUTC + j];
        #pragma unroll
        for (int r = 0; r < 4; ++r) acc[r] += xs[msub + 4 * r][k] * w;
    }
    #pragma unroll
    for (int r = 0; r < 4; ++r)
        h2[(size_t)(n0 + msub + 4 * r) * OUTC + j] = acc[r];
}

// ------------- Layer 2 attention logits: al2/ar2 [N] ------------------------
__global__ __launch_bounds__(256) void attn_logits2(
        const float* __restrict__ h2, const float* __restrict__ a_src,
        const float* __restrict__ a_dst, float* __restrict__ al,
        float* __restrict__ ar) {
    const int n = blockIdx.x * 4 + (threadIdx.x >> 6);
    const int c = threadIdx.x & 63;
    float v = h2[(size_t)n * OUTC + c];
    float s = v * a_src[c];
    float d = v * a_dst[c];
    #pragma unroll
    for (int o = 32; o; o >>= 1) {
        s += __shfl_down(s, o, 64);
        d += __shfl_down(d, o, 64);
    }
    if (c == 0) { al[n] = s; ar[n] = d; }
}

// ===== Layer 2 fused: denom + weighted gather + bias (wave per dst) =========
__global__ __launch_bounds__(256) void aggr2_csr(
        const int* __restrict__ rowstart, const int* __restrict__ col,
        const float* __restrict__ al, const float* __restrict__ ar,
        const float* __restrict__ h2, const float* __restrict__ b2,
        float* __restrict__ out) {
    const int lane = threadIdx.x & 63;
    const int d = blockIdx.x * 4 + (threadIdx.x >> 6);
    if (d >= N_NODES) return;
    const int beg = rowstart[d], end = rowstart[d + 1];
    const float ard = ar[d];

    // pass 1: denominator (edge-parallel over all 64 lanes)
    float denom = 0.f;
    for (int i = beg + lane; i < end; i += 64) {
        float eh = al[col[i]] + ard;
        eh = eh > 0.f ? eh : 0.2f * eh;
        denom += expf(eh);
    }
    #pragma unroll
    for (int o = 1; o < 64; o <<= 1) denom += __shfl_xor(denom, o, 64);
    denom += 1e-16f;

    // pass 2: weighted accumulation (lane = channel)
    float acc = 0.f;
    for (int i = beg; i < end; ++i) {
        int s = col[i];
        float eh = al[s] + ard;
        eh = eh > 0.f ? eh : 0.2f * eh;
        float w = expf(eh) / denom;
        acc += w * h2[(size_t)s * OUTC + lane];
    }
    out[(size_t)d * OUTC + lane] = acc + b2[lane];
}

extern "C" void kernel_launch(void* const* d_in, const int* in_sizes, int n_in,
                              void* d_out, int out_size, void* d_ws, size_t ws_size,
                              hipStream_t stream) {
    const float* x      = (const float*)d_in[0];
    const int*   ei     = (const int*)  d_in[1];
    const float* W1     = (const float*)d_in[2];
    const float* a_src1 = (const float*)d_in[3];
    const float* a_dst1 = (const float*)d_in[4];
    const float* b1     = (const float*)d_in[5];
    const float* W2     = (const float*)d_in[6];
    const float* a_src2 = (const float*)d_in[7];
    const float* a_dst2 = (const float*)d_in[8];
    const float* b2     = (const float*)d_in[9];
    float* out = (float*)d_out;

    // ---- workspace layout ----
    char* p = (char*)d_ws;
    float* h1   = (float*)p;  p += (size_t)N_NODES * HC * sizeof(float);    // 51.2 MB
    float* out1 = (float*)p;  p += (size_t)N_NODES * HC * sizeof(float);    // 51.2 MB
    float* h2   = (float*)p;  p += (size_t)N_NODES * OUTC * sizeof(float);  // 12.8 MB
    float* al1  = (float*)p;  p += (size_t)N_NODES * HEADS * sizeof(float);
    float* ar1  = (float*)p;  p += (size_t)N_NODES * HEADS * sizeof(float);
    float* al2  = (float*)p;  p += (size_t)N_NODES * sizeof(float);
    float* ar2  = (float*)p;  p += (size_t)N_NODES * sizeof(float);
    int* deg      = (int*)p;  p += (size_t)N_NODES * sizeof(int);
    int* inc      = (int*)p;  p += (size_t)N_NODES * sizeof(int);
    int* bsum     = (int*)p;  p += (size_t)NSCAN_BLOCKS * sizeof(int);
    int* rowstart = (int*)p;  p += (size_t)(N_NODES + 1) * sizeof(int);
    int* cursor   = (int*)p;  p += (size_t)N_NODES * sizeof(int);
    int* col      = (int*)p;  p += (size_t)E_TOT * sizeof(int);

    // ---- CSR build ----
    hipMemsetAsync(deg, 0, (size_t)N_NODES * sizeof(int), stream);
    hist_kernel   <<<(E_TOT + 255)/256, 256, 0, stream>>>(ei, deg);
    scan1_kernel  <<<NSCAN_BLOCKS, 1024, 0, stream>>>(deg, inc, bsum);
    scan2_kernel  <<<1, 64, 0, stream>>>(bsum);
    finalize_kernel<<<(N_NODES + 255)/256, 256, 0, stream>>>(inc, bsum, rowstart, cursor);
    scatter_kernel<<<(E_TOT + 255)/256, 256, 0, stream>>>(ei, cursor, col);

    // ---- layer 1 ----
    gemm1_kernel<<<N_NODES/8, 256, 0, stream>>>(x, W1, h1);
    attn_logits1<<<N_NODES, 256, 0, stream>>>(h1, a_src1, a_dst1, al1, ar1);
    aggr1_csr   <<<(N_NODES + 3)/4, 256, 0, stream>>>(rowstart, col, al1, ar1, h1, b1, out1);

    // ---- layer 2 ----
    gemm2_kernel<<<N_NODES/16, 256, 0, stream>>>(out1, W2, h2);
    attn_logits2<<<N_NODES/4, 256, 0, stream>>>(h2, a_src2, a_dst2, al2, ar2);
    aggr2_csr   <<<(N_NODES + 3)/4, 256, 0, stream>>>(rowstart, col, al2, ar2, h2, b2, out);
}

// Round 3
// 447.587 us; speedup vs baseline: 3.2388x; 1.0875x over previous
//
#include <hip/hip_runtime.h>
#include <cstdint>

#define N_NODES 50000
#define N_EDGES 800000
#define E_TOT   (N_EDGES + N_NODES)   // 850000 with self-loops
#define IN_CH   128
#define HEADS   8
#define CCH     32
#define HC      256                    // HEADS*CCH
#define OUTC    64

// bf16 helpers (RNE rounding on pack)
static __device__ __forceinline__ unsigned short f2bf(float f) {
    unsigned u = __float_as_uint(f);
    u = u + 0x7fffu + ((u >> 16) & 1u);
    return (unsigned short)(u >> 16);
}
static __device__ __forceinline__ float bf2f(unsigned short h) {
    return __uint_as_float((unsigned)h << 16);
}

// ======================= CSR construction (per call) ========================
__global__ __launch_bounds__(256) void hist_kernel(
        const int* __restrict__ ei, int* __restrict__ deg) {
    int e = blockIdx.x * 256 + threadIdx.x;
    if (e >= E_TOT) return;
    int dv = (e < N_EDGES) ? ei[N_EDGES + e] : (e - N_EDGES);
    atomicAdd(&deg[dv], 1);
}

__global__ __launch_bounds__(1024) void scan1_kernel(
        const int* __restrict__ deg, int* __restrict__ inc, int* __restrict__ bsum) {
    __shared__ int sh[1024];
    const int tid = threadIdx.x;
    const int i = blockIdx.x * 1024 + tid;
    sh[tid] = (i < N_NODES) ? deg[i] : 0;
    __syncthreads();
    for (int o = 1; o < 1024; o <<= 1) {
        int t = (tid >= o) ? sh[tid - o] : 0;
        __syncthreads();
        sh[tid] += t;
        __syncthreads();
    }
    if (i < N_NODES) inc[i] = sh[tid];
    if (tid == 1023) bsum[blockIdx.x] = sh[1023];
}

#define NSCAN_BLOCKS ((N_NODES + 1023) / 1024)   // 49
__global__ void scan2_kernel(int* __restrict__ bsum) {
    if (threadIdx.x == 0 && blockIdx.x == 0) {
        int acc = 0;
        for (int k = 0; k < NSCAN_BLOCKS; ++k) { int t = bsum[k]; bsum[k] = acc; acc += t; }
    }
}

__global__ __launch_bounds__(256) void finalize_kernel(
        const int* __restrict__ inc, const int* __restrict__ bsum,
        int* __restrict__ rowstart, int* __restrict__ cursor) {
    int i = blockIdx.x * 256 + threadIdx.x;
    if (i >= N_NODES) return;
    int v = inc[i] + bsum[i >> 10];
    rowstart[i + 1] = v;
    if (i + 1 < N_NODES) cursor[i + 1] = v;
    if (i == 0) { rowstart[0] = 0; cursor[0] = 0; }
}

__global__ __launch_bounds__(256) void scatter_kernel(
        const int* __restrict__ ei, int* __restrict__ cursor, int* __restrict__ col) {
    int e = blockIdx.x * 256 + threadIdx.x;
    if (e >= E_TOT) return;
    int sv, dv;
    if (e < N_EDGES) { sv = ei[e]; dv = ei[N_EDGES + e]; }
    else             { sv = dv = e - N_EDGES; }
    int pos = atomicAdd(&cursor[dv], 1);
    col[pos] = sv;
}

// ====== Layer 1 GEMM fused with attention logits: h1b(bf16), al1, ar1 =======
__global__ __launch_bounds__(256) void gemm1_fused(
        const float* __restrict__ x, const float* __restrict__ W1,
        const float* __restrict__ a_src, const float* __restrict__ a_dst,
        unsigned short* __restrict__ h1b, float* __restrict__ al,
        float* __restrict__ ar) {
    __shared__ float xs[8][IN_CH];
    const int j  = threadIdx.x;            // output column 0..255, head j>>5
    const int n0 = blockIdx.x * 8;
    for (int i = threadIdx.x; i < 8 * IN_CH; i += 256) {
        int m = i >> 7, k = i & (IN_CH - 1);
        xs[m][k] = x[(size_t)(n0 + m) * IN_CH + k];
    }
    __syncthreads();
    float acc[8] = {0.f,0.f,0.f,0.f,0.f,0.f,0.f,0.f};
    for (int k = 0; k < IN_CH; ++k) {
        float w = W1[k * HC + j];
        #pragma unroll
        for (int m = 0; m < 8; ++m) acc[m] += xs[m][k] * w;
    }
    #pragma unroll
    for (int m = 0; m < 8; ++m)
        h1b[(size_t)(n0 + m) * HC + j] = f2bf(acc[m]);
    // logits: reduce over the 32 channels of head j>>5 (consecutive lanes)
    const float asj = a_src[j], adj = a_dst[j];
    #pragma unroll
    for (int m = 0; m < 8; ++m) {
        float s = acc[m] * asj, d = acc[m] * adj;
        #pragma unroll
        for (int o = 16; o; o >>= 1) {
            s += __shfl_down(s, o, 32);
            d += __shfl_down(d, o, 32);
        }
        if ((j & 31) == 0) {
            al[(n0 + m) * HEADS + (j >> 5)] = s;
            ar[(n0 + m) * HEADS + (j >> 5)] = d;
        }
    }
}

// ===== Layer 1 fused aggregation: denom + gather + bias + ELU -> bf16 =======
__global__ __launch_bounds__(256) void aggr1_csr(
        const int* __restrict__ rowstart, const int* __restrict__ col,
        const float* __restrict__ al, const float* __restrict__ ar,
        const unsigned short* __restrict__ h1b, const float* __restrict__ b1,
        unsigned short* __restrict__ out1b) {
    const int lane = threadIdx.x & 63;
    const int d = blockIdx.x * 4 + (threadIdx.x >> 6);
    if (d >= N_NODES) return;
    const int beg = rowstart[d], end = rowstart[d + 1];

    // pass 1: softmax denominator. lane handles head hh=lane&7, edge group lane>>3
    const int hh = lane & 7;
    const float ar_hh = ar[d * HEADS + hh];
    float denom = 0.f;
    for (int i = beg + (lane >> 3); i < end; i += 8) {
        int s = col[i];
        float eh = al[s * HEADS + hh] + ar_hh;
        eh = eh > 0.f ? eh : 0.2f * eh;
        denom += expf(eh);
    }
    denom += __shfl_xor(denom, 8, 64);
    denom += __shfl_xor(denom, 16, 64);
    denom += __shfl_xor(denom, 32, 64);
    const int h = lane >> 3;                  // head of my 4 channels
    const float mydenom = __shfl(denom, h, 64) + 1e-16f;

    // pass 2: weighted accumulation of h1b[src] (bf16 gather, fp32 accumulate)
    const float ar_h = ar[d * HEADS + h];
    float4 acc = {0.f, 0.f, 0.f, 0.f};
    for (int i = beg; i < end; ++i) {
        int s = col[i];
        float eh = al[s * HEADS + h] + ar_h;
        eh = eh > 0.f ? eh : 0.2f * eh;
        float w = expf(eh) / mydenom;
        const ushort4 hv = *(const ushort4*)&h1b[(size_t)s * HC + 4 * lane];
        acc.x += w * bf2f(hv.x); acc.y += w * bf2f(hv.y);
        acc.z += w * bf2f(hv.z); acc.w += w * bf2f(hv.w);
    }
    const float4 bb = *(const float4*)&b1[4 * lane];
    acc.x += bb.x; acc.y += bb.y; acc.z += bb.z; acc.w += bb.w;
    acc.x = acc.x > 0.f ? acc.x : expf(acc.x) - 1.f;
    acc.y = acc.y > 0.f ? acc.y : expf(acc.y) - 1.f;
    acc.z = acc.z > 0.f ? acc.z : expf(acc.z) - 1.f;
    acc.w = acc.w > 0.f ? acc.w : expf(acc.w) - 1.f;
    ushort4 ov = { f2bf(acc.x), f2bf(acc.y), f2bf(acc.z), f2bf(acc.w) };
    *(ushort4*)&out1b[(size_t)d * HC + 4 * lane] = ov;
}

// ====== Layer 2 GEMM fused with logits: h2b(bf16), al2, ar2 =================
__global__ __launch_bounds__(256) void gemm2_fused(
        const unsigned short* __restrict__ hinb, const float* __restrict__ W2,
        const float* __restrict__ a_src, const float* __restrict__ a_dst,
        unsigned short* __restrict__ h2b, float* __restrict__ al,
        float* __restrict__ ar) {
    __shared__ float xs[16][HC];           // 16 KB
    const int j    = threadIdx.x & 63;     // output column
    const int msub = threadIdx.x >> 6;     // 0..3
    const int n0   = blockIdx.x * 16;
    for (int i = threadIdx.x; i < 16 * HC; i += 256) {
        int m = i >> 8, k = i & (HC - 1);
        xs[m][k] = bf2f(hinb[(size_t)(n0 + m) * HC + k]);
    }
    __syncthreads();
    float acc[4] = {0.f,0.f,0.f,0.f};
    for (int k = 0; k < HC; ++k) {
        float w = W2[k * OUTC + j];
        #pragma unroll
        for (int r = 0; r < 4; ++r) acc[r] += xs[msub + 4 * r][k] * w;
    }
    const float asj = a_src[j], adj = a_dst[j];
    #pragma unroll
    for (int r = 0; r < 4; ++r) {
        int n = n0 + msub + 4 * r;
        h2b[(size_t)n * OUTC + j] = f2bf(acc[r]);
        float s = acc[r] * asj, d = acc[r] * adj;
        #pragma unroll
        for (int o = 32; o; o >>= 1) {
            s += __shfl_down(s, o, 64);
            d += __shfl_down(d, o, 64);
        }
        if (j == 0) { al[n] = s; ar[n] = d; }
    }
}

// ===== Layer 2 fused aggregation: denom + gather + bias (fp32 out) ==========
__global__ __launch_bounds__(256) void aggr2_csr(
        const int* __restrict__ rowstart, const int* __restrict__ col,
        const float* __restrict__ al, const float* __restrict__ ar,
        const unsigned short* __restrict__ h2b, const float* __restrict__ b2,
        float* __restrict__ out) {
    const int lane = threadIdx.x & 63;
    const int d = blockIdx.x * 4 + (threadIdx.x >> 6);
    if (d >= N_NODES) return;
    const int beg = rowstart[d], end = rowstart[d + 1];
    const float ard = ar[d];

    float denom = 0.f;
    for (int i = beg + lane; i < end; i += 64) {
        float eh = al[col[i]] + ard;
        eh = eh > 0.f ? eh : 0.2f * eh;
        denom += expf(eh);
    }
    #pragma unroll
    for (int o = 1; o < 64; o <<= 1) denom += __shfl_xor(denom, o, 64);
    denom += 1e-16f;

    float acc = 0.f;
    for (int i = beg; i < end; ++i) {
        int s = col[i];
        float eh = al[s] + ard;
        eh = eh > 0.f ? eh : 0.2f * eh;
        float w = expf(eh) / denom;
        acc += w * bf2f(h2b[(size_t)s * OUTC + lane]);
    }
    out[(size_t)d * OUTC + lane] = acc + b2[lane];
}

extern "C" void kernel_launch(void* const* d_in, const int* in_sizes, int n_in,
                              void* d_out, int out_size, void* d_ws, size_t ws_size,
                              hipStream_t stream) {
    const float* x      = (const float*)d_in[0];
    const int*   ei     = (const int*)  d_in[1];
    const float* W1     = (const float*)d_in[2];
    const float* a_src1 = (const float*)d_in[3];
    const float* a_dst1 = (const float*)d_in[4];
    const float* b1     = (const float*)d_in[5];
    const float* W2     = (const float*)d_in[6];
    const float* a_src2 = (const float*)d_in[7];
    const float* a_dst2 = (const float*)d_in[8];
    const float* b2     = (const float*)d_in[9];
    float* out = (float*)d_out;

    // ---- workspace layout ----
    char* p = (char*)d_ws;
    unsigned short* h1b   = (unsigned short*)p; p += (size_t)N_NODES * HC * 2;   // 25.6 MB
    unsigned short* out1b = (unsigned short*)p; p += (size_t)N_NODES * HC * 2;   // 25.6 MB
    unsigned short* h2b   = (unsigned short*)p; p += (size_t)N_NODES * OUTC * 2; // 6.4 MB
    float* al1  = (float*)p;  p += (size_t)N_NODES * HEADS * sizeof(float);
    float* ar1  = (float*)p;  p += (size_t)N_NODES * HEADS * sizeof(float);
    float* al2  = (float*)p;  p += (size_t)N_NODES * sizeof(float);
    float* ar2  = (float*)p;  p += (size_t)N_NODES * sizeof(float);
    int* deg      = (int*)p;  p += (size_t)N_NODES * sizeof(int);
    int* inc      = (int*)p;  p += (size_t)N_NODES * sizeof(int);
    int* bsum     = (int*)p;  p += (size_t)NSCAN_BLOCKS * sizeof(int);
    int* rowstart = (int*)p;  p += (size_t)(N_NODES + 1) * sizeof(int);
    int* cursor   = (int*)p;  p += (size_t)N_NODES * sizeof(int);
    int* col      = (int*)p;  p += (size_t)E_TOT * sizeof(int);

    // ---- CSR build ----
    hipMemsetAsync(deg, 0, (size_t)N_NODES * sizeof(int), stream);
    hist_kernel    <<<(E_TOT + 255)/256, 256, 0, stream>>>(ei, deg);
    scan1_kernel   <<<NSCAN_BLOCKS, 1024, 0, stream>>>(deg, inc, bsum);
    scan2_kernel   <<<1, 64, 0, stream>>>(bsum);
    finalize_kernel<<<(N_NODES + 255)/256, 256, 0, stream>>>(inc, bsum, rowstart, cursor);
    scatter_kernel <<<(E_TOT + 255)/256, 256, 0, stream>>>(ei, cursor, col);

    // ---- layer 1 ----
    gemm1_fused<<<N_NODES/8, 256, 0, stream>>>(x, W1, a_src1, a_dst1, h1b, al1, ar1);
    aggr1_csr  <<<(N_NODES + 3)/4, 256, 0, stream>>>(rowstart, col, al1, ar1, h1b, b1, out1b);

    // ---- layer 2 ----
    gemm2_fused<<<N_NODES/16, 256, 0, stream>>>(out1b, W2, a_src2, a_dst2, h2b, al2, ar2);
    aggr2_csr  <<<(N_NODES + 3)/4, 256, 0, stream>>>(rowstart, col, al2, ar2, h2b, b2, out);
}

// Round 4
// 417.976 us; speedup vs baseline: 3.4682x; 1.0708x over previous
//
#include <hip/hip_runtime.h>
#include <cstdint>

#define N_NODES 50000
#define N_EDGES 800000
#define E_TOT   (N_EDGES + N_NODES)   // 850000 with self-loops
#define IN_CH   128
#define HEADS   8
#define CCH     32
#define HC      256                    // HEADS*CCH
#define OUTC    64

// bf16 helpers (RNE rounding on pack)
static __device__ __forceinline__ unsigned short f2bf(float f) {
    unsigned u = __float_as_uint(f);
    u = u + 0x7fffu + ((u >> 16) & 1u);
    return (unsigned short)(u >> 16);
}
static __device__ __forceinline__ float bf2f(unsigned short h) {
    return __uint_as_float((unsigned)h << 16);
}
static __device__ __forceinline__ unsigned pack2(float lo, float hi) {
    return (unsigned)f2bf(lo) | ((unsigned)f2bf(hi) << 16);
}
static __device__ __forceinline__ float lrexp(float v) {
    v = v > 0.f ? v : 0.2f * v;        // LeakyReLU(0.2)
    return expf(v);
}

// ======================= CSR construction (per call) ========================
__global__ __launch_bounds__(256) void hist_kernel(
        const int* __restrict__ ei, int* __restrict__ deg) {
    int e = blockIdx.x * 256 + threadIdx.x;
    if (e >= E_TOT) return;
    int dv = (e < N_EDGES) ? ei[N_EDGES + e] : (e - N_EDGES);
    atomicAdd(&deg[dv], 1);
}

__global__ __launch_bounds__(1024) void scan1_kernel(
        const int* __restrict__ deg, int* __restrict__ inc, int* __restrict__ bsum) {
    __shared__ int sh[1024];
    const int tid = threadIdx.x;
    const int i = blockIdx.x * 1024 + tid;
    sh[tid] = (i < N_NODES) ? deg[i] : 0;
    __syncthreads();
    for (int o = 1; o < 1024; o <<= 1) {
        int t = (tid >= o) ? sh[tid - o] : 0;
        __syncthreads();
        sh[tid] += t;
        __syncthreads();
    }
    if (i < N_NODES) inc[i] = sh[tid];
    if (tid == 1023) bsum[blockIdx.x] = sh[1023];
}

#define NSCAN_BLOCKS ((N_NODES + 1023) / 1024)   // 49
__global__ void scan2_kernel(int* __restrict__ bsum) {
    if (threadIdx.x == 0 && blockIdx.x == 0) {
        int acc = 0;
        for (int k = 0; k < NSCAN_BLOCKS; ++k) { int t = bsum[k]; bsum[k] = acc; acc += t; }
    }
}

__global__ __launch_bounds__(256) void finalize_kernel(
        const int* __restrict__ inc, const int* __restrict__ bsum,
        int* __restrict__ rowstart, int* __restrict__ cursor) {
    int i = blockIdx.x * 256 + threadIdx.x;
    if (i >= N_NODES) return;
    int v = inc[i] + bsum[i >> 10];
    rowstart[i + 1] = v;
    if (i + 1 < N_NODES) cursor[i + 1] = v;
    if (i == 0) { rowstart[0] = 0; cursor[0] = 0; }
}

__global__ __launch_bounds__(256) void scatter_kernel(
        const int* __restrict__ ei, int* __restrict__ cursor,
        int* __restrict__ col, int* __restrict__ row) {
    int e = blockIdx.x * 256 + threadIdx.x;
    if (e >= E_TOT) return;
    int sv, dv;
    if (e < N_EDGES) { sv = ei[e]; dv = ei[N_EDGES + e]; }
    else             { sv = dv = e - N_EDGES; }
    int pos = atomicAdd(&cursor[dv], 1);
    col[pos] = sv;
    row[pos] = dv;
}

// ====== Layer 1 GEMM fused with attention logits: h1b(bf16), al1, ar1 =======
__global__ __launch_bounds__(256) void gemm1_fused(
        const float* __restrict__ x, const float* __restrict__ W1,
        const float* __restrict__ a_src, const float* __restrict__ a_dst,
        unsigned short* __restrict__ h1b, float* __restrict__ al,
        float* __restrict__ ar) {
    __shared__ float xs[8][IN_CH];
    const int j  = threadIdx.x;            // output column 0..255, head j>>5
    const int n0 = blockIdx.x * 8;
    for (int i = threadIdx.x; i < 8 * IN_CH; i += 256) {
        int m = i >> 7, k = i & (IN_CH - 1);
        xs[m][k] = x[(size_t)(n0 + m) * IN_CH + k];
    }
    __syncthreads();
    float acc[8] = {0.f,0.f,0.f,0.f,0.f,0.f,0.f,0.f};
    for (int k = 0; k < IN_CH; ++k) {
        float w = W1[k * HC + j];
        #pragma unroll
        for (int m = 0; m < 8; ++m) acc[m] += xs[m][k] * w;
    }
    #pragma unroll
    for (int m = 0; m < 8; ++m)
        h1b[(size_t)(n0 + m) * HC + j] = f2bf(acc[m]);
    const float asj = a_src[j], adj = a_dst[j];
    #pragma unroll
    for (int m = 0; m < 8; ++m) {
        float s = acc[m] * asj, d = acc[m] * adj;
        #pragma unroll
        for (int o = 16; o; o >>= 1) {
            s += __shfl_down(s, o, 32);
            d += __shfl_down(d, o, 32);
        }
        if ((j & 31) == 0) {
            al[(n0 + m) * HEADS + (j >> 5)] = s;
            ar[(n0 + m) * HEADS + (j >> 5)] = d;
        }
    }
}

// ===== Edge-parallel exp(leaky(logit)) precompute, layer 1 (bf16 out) =======
__global__ __launch_bounds__(256) void edge_alpha1(
        const int* __restrict__ col, const int* __restrict__ row,
        const float* __restrict__ al, const float* __restrict__ ar,
        unsigned short* __restrict__ expv) {
    int pos = blockIdx.x * 256 + threadIdx.x;
    if (pos >= E_TOT) return;
    int s = col[pos], d = row[pos];
    const float4* As = (const float4*)&al[s * HEADS];
    const float4* Ad = (const float4*)&ar[d * HEADS];
    float4 a0 = As[0], a1 = As[1], r0 = Ad[0], r1 = Ad[1];
    uint4 o;
    o.x = pack2(lrexp(a0.x + r0.x), lrexp(a0.y + r0.y));
    o.y = pack2(lrexp(a0.z + r0.z), lrexp(a0.w + r0.w));
    o.z = pack2(lrexp(a1.x + r1.x), lrexp(a1.y + r1.y));
    o.w = pack2(lrexp(a1.z + r1.z), lrexp(a1.w + r1.w));
    *(uint4*)&expv[(size_t)pos * 8] = o;
}

// ===== Layer 1 aggregation: denom + gather + bias + ELU -> bf16 =============
__global__ __launch_bounds__(256) void aggr1_csr(
        const int* __restrict__ rowstart, const int* __restrict__ col,
        const unsigned short* __restrict__ expv,
        const unsigned short* __restrict__ h1b, const float* __restrict__ b1,
        unsigned short* __restrict__ out1b) {
    const int lane = threadIdx.x & 63;
    const int d = blockIdx.x * 4 + (threadIdx.x >> 6);
    if (d >= N_NODES) return;
    const int beg = rowstart[d], end = rowstart[d + 1];

    // pass 1: denom per head; flattened index keeps lane on fixed head lane&7
    float denom = 0.f;
    for (int i = beg * 8 + lane; i < end * 8; i += 64)
        denom += bf2f(expv[i]);
    denom += __shfl_xor(denom, 8, 64);
    denom += __shfl_xor(denom, 16, 64);
    denom += __shfl_xor(denom, 32, 64);          // lanes with same (lane&7) share
    const int h = lane >> 3;                     // head of my 4 channels
    const float inv = 1.f / (__shfl(denom, h, 64) + 1e-16f);

    // pass 2: weighted accumulation (no exp, no div)
    float4 acc = {0.f, 0.f, 0.f, 0.f};
    for (int i = beg; i < end; ++i) {
        int s = col[i];
        float w = bf2f(expv[i * 8 + h]) * inv;
        const ushort4 hv = *(const ushort4*)&h1b[(size_t)s * HC + 4 * lane];
        acc.x += w * bf2f(hv.x); acc.y += w * bf2f(hv.y);
        acc.z += w * bf2f(hv.z); acc.w += w * bf2f(hv.w);
    }
    const float4 bb = *(const float4*)&b1[4 * lane];
    acc.x += bb.x; acc.y += bb.y; acc.z += bb.z; acc.w += bb.w;
    acc.x = acc.x > 0.f ? acc.x : expf(acc.x) - 1.f;
    acc.y = acc.y > 0.f ? acc.y : expf(acc.y) - 1.f;
    acc.z = acc.z > 0.f ? acc.z : expf(acc.z) - 1.f;
    acc.w = acc.w > 0.f ? acc.w : expf(acc.w) - 1.f;
    ushort4 ov = { f2bf(acc.x), f2bf(acc.y), f2bf(acc.z), f2bf(acc.w) };
    *(ushort4*)&out1b[(size_t)d * HC + 4 * lane] = ov;
}

// ====== Layer 2 GEMM fused with logits: h2b(bf16), al2, ar2 =================
__global__ __launch_bounds__(256) void gemm2_fused(
        const unsigned short* __restrict__ hinb, const float* __restrict__ W2,
        const float* __restrict__ a_src, const float* __restrict__ a_dst,
        unsigned short* __restrict__ h2b, float* __restrict__ al,
        float* __restrict__ ar) {
    __shared__ float xs[16][HC];
    const int j    = threadIdx.x & 63;
    const int msub = threadIdx.x >> 6;
    const int n0   = blockIdx.x * 16;
    for (int i = threadIdx.x; i < 16 * HC; i += 256) {
        int m = i >> 8, k = i & (HC - 1);
        xs[m][k] = bf2f(hinb[(size_t)(n0 + m) * HC + k]);
    }
    __syncthreads();
    float acc[4] = {0.f,0.f,0.f,0.f};
    for (int k = 0; k < HC; ++k) {
        float w = W2[k * OUTC + j];
        #pragma unroll
        for (int r = 0; r < 4; ++r) acc[r] += xs[msub + 4 * r][k] * w;
    }
    const float asj = a_src[j], adj = a_dst[j];
    #pragma unroll
    for (int r = 0; r < 4; ++r) {
        int n = n0 + msub + 4 * r;
        h2b[(size_t)n * OUTC + j] = f2bf(acc[r]);
        float s = acc[r] * asj, d = acc[r] * adj;
        #pragma unroll
        for (int o = 32; o; o >>= 1) {
            s += __shfl_down(s, o, 64);
            d += __shfl_down(d, o, 64);
        }
        if (j == 0) { al[n] = s; ar[n] = d; }
    }
}

// ===== Edge-parallel exp precompute, layer 2 (fp32 out) =====================
__global__ __launch_bounds__(256) void edge_alpha2(
        const int* __restrict__ col, const int* __restrict__ row,
        const float* __restrict__ al, const float* __restrict__ ar,
        float* __restrict__ expv) {
    int pos = blockIdx.x * 256 + threadIdx.x;
    if (pos >= E_TOT) return;
    expv[pos] = lrexp(al[col[pos]] + ar[row[pos]]);
}

// ===== Layer 2 aggregation: denom + gather + bias (fp32 out) ================
__global__ __launch_bounds__(256) void aggr2_csr(
        const int* __restrict__ rowstart, const int* __restrict__ col,
        const float* __restrict__ expv,
        const unsigned short* __restrict__ h2b, const float* __restrict__ b2,
        float* __restrict__ out) {
    const int lane = threadIdx.x & 63;
    const int d = blockIdx.x * 4 + (threadIdx.x >> 6);
    if (d >= N_NODES) return;
    const int beg = rowstart[d], end = rowstart[d + 1];

    float denom = 0.f;
    for (int i = beg + lane; i < end; i += 64)
        denom += expv[i];
    #pragma unroll
    for (int o = 1; o < 64; o <<= 1) denom += __shfl_xor(denom, o, 64);
    const float inv = 1.f / (denom + 1e-16f);

    float acc = 0.f;
    for (int i = beg; i < end; ++i) {
        int s = col[i];
        float w = expv[i] * inv;
        acc += w * bf2f(h2b[(size_t)s * OUTC + lane]);
    }
    out[(size_t)d * OUTC + lane] = acc + b2[lane];
}

extern "C" void kernel_launch(void* const* d_in, const int* in_sizes, int n_in,
                              void* d_out, int out_size, void* d_ws, size_t ws_size,
                              hipStream_t stream) {
    const float* x      = (const float*)d_in[0];
    const int*   ei     = (const int*)  d_in[1];
    const float* W1     = (const float*)d_in[2];
    const float* a_src1 = (const float*)d_in[3];
    const float* a_dst1 = (const float*)d_in[4];
    const float* b1     = (const float*)d_in[5];
    const float* W2     = (const float*)d_in[6];
    const float* a_src2 = (const float*)d_in[7];
    const float* a_dst2 = (const float*)d_in[8];
    const float* b2     = (const float*)d_in[9];
    float* out = (float*)d_out;

    // ---- workspace layout ----
    char* p = (char*)d_ws;
    unsigned short* h1b   = (unsigned short*)p; p += (size_t)N_NODES * HC * 2;   // 25.6 MB
    unsigned short* out1b = (unsigned short*)p; p += (size_t)N_NODES * HC * 2;   // 25.6 MB
    unsigned short* h2b   = (unsigned short*)p; p += (size_t)N_NODES * OUTC * 2; // 6.4 MB
    unsigned short* expv1 = (unsigned short*)p; p += (size_t)E_TOT * 8 * 2;      // 13.6 MB
    float* expv2 = (float*)p; p += (size_t)E_TOT * sizeof(float);                // 3.4 MB
    float* al1  = (float*)p;  p += (size_t)N_NODES * HEADS * sizeof(float);
    float* ar1  = (float*)p;  p += (size_t)N_NODES * HEADS * sizeof(float);
    float* al2  = (float*)p;  p += (size_t)N_NODES * sizeof(float);
    float* ar2  = (float*)p;  p += (size_t)N_NODES * sizeof(float);
    int* deg      = (int*)p;  p += (size_t)N_NODES * sizeof(int);
    int* inc      = (int*)p;  p += (size_t)N_NODES * sizeof(int);
    int* bsum     = (int*)p;  p += (size_t)NSCAN_BLOCKS * sizeof(int);
    int* rowstart = (int*)p;  p += (size_t)(N_NODES + 1) * sizeof(int);
    int* cursor   = (int*)p;  p += (size_t)N_NODES * sizeof(int);
    int* col      = (int*)p;  p += (size_t)E_TOT * sizeof(int);
    int* row      = (int*)p;  p += (size_t)E_TOT * sizeof(int);

    // ---- CSR build ----
    hipMemsetAsync(deg, 0, (size_t)N_NODES * sizeof(int), stream);
    hist_kernel    <<<(E_TOT + 255)/256, 256, 0, stream>>>(ei, deg);
    scan1_kernel   <<<NSCAN_BLOCKS, 1024, 0, stream>>>(deg, inc, bsum);
    scan2_kernel   <<<1, 64, 0, stream>>>(bsum);
    finalize_kernel<<<(N_NODES + 255)/256, 256, 0, stream>>>(inc, bsum, rowstart, cursor);
    scatter_kernel <<<(E_TOT + 255)/256, 256, 0, stream>>>(ei, cursor, col, row);

    // ---- layer 1 ----
    gemm1_fused<<<N_NODES/8, 256, 0, stream>>>(x, W1, a_src1, a_dst1, h1b, al1, ar1);
    edge_alpha1<<<(E_TOT + 255)/256, 256, 0, stream>>>(col, row, al1, ar1, expv1);
    aggr1_csr  <<<(N_NODES + 3)/4, 256, 0, stream>>>(rowstart, col, expv1, h1b, b1, out1b);

    // ---- layer 2 ----
    gemm2_fused<<<N_NODES/16, 256, 0, stream>>>(out1b, W2, a_src2, a_dst2, h2b, al2, ar2);
    edge_alpha2<<<(E_TOT + 255)/256, 256, 0, stream>>>(col, row, al2, ar2, expv2);
    aggr2_csr  <<<(N_NODES + 3)/4, 256, 0, stream>>>(rowstart, col, expv2, h2b, b2, out);
}

// Round 5
// 346.657 us; speedup vs baseline: 4.1818x; 1.2057x over previous
//
#include <hip/hip_runtime.h>
#include <cstdint>

#define N_NODES 50000
#define N_EDGES 800000
#define E_TOT   (N_EDGES + N_NODES)   // 850000 with self-loops
#define IN_CH   128
#define HEADS   8
#define CCH     32
#define HC      256                    // HEADS*CCH
#define OUTC    64

// bf16 helpers (RNE rounding on pack)
static __device__ __forceinline__ unsigned short f2bf(float f) {
    unsigned u = __float_as_uint(f);
    u = u + 0x7fffu + ((u >> 16) & 1u);
    return (unsigned short)(u >> 16);
}
static __device__ __forceinline__ float bf2f(unsigned short h) {
    return __uint_as_float((unsigned)h << 16);
}
static __device__ __forceinline__ unsigned pack2(float lo, float hi) {
    return (unsigned)f2bf(lo) | ((unsigned)f2bf(hi) << 16);
}
static __device__ __forceinline__ float lrexp(float v) {
    v = v > 0.f ? v : 0.2f * v;        // LeakyReLU(0.2)
    return expf(v);
}

// ======================= CSR construction (per call) ========================
__global__ __launch_bounds__(256) void hist_kernel(
        const int* __restrict__ ei, int* __restrict__ deg) {
    int e = blockIdx.x * 256 + threadIdx.x;
    if (e >= E_TOT) return;
    int dv = (e < N_EDGES) ? ei[N_EDGES + e] : (e - N_EDGES);
    atomicAdd(&deg[dv], 1);
}

__global__ __launch_bounds__(1024) void scan1_kernel(
        const int* __restrict__ deg, int* __restrict__ inc, int* __restrict__ bsum) {
    __shared__ int sh[1024];
    const int tid = threadIdx.x;
    const int i = blockIdx.x * 1024 + tid;
    sh[tid] = (i < N_NODES) ? deg[i] : 0;
    __syncthreads();
    for (int o = 1; o < 1024; o <<= 1) {
        int t = (tid >= o) ? sh[tid - o] : 0;
        __syncthreads();
        sh[tid] += t;
        __syncthreads();
    }
    if (i < N_NODES) inc[i] = sh[tid];
    if (tid == 1023) bsum[blockIdx.x] = sh[1023];
}

#define NSCAN_BLOCKS ((N_NODES + 1023) / 1024)   // 49
__global__ void scan2_kernel(int* __restrict__ bsum) {
    if (threadIdx.x == 0 && blockIdx.x == 0) {
        int acc = 0;
        for (int k = 0; k < NSCAN_BLOCKS; ++k) { int t = bsum[k]; bsum[k] = acc; acc += t; }
    }
}

__global__ __launch_bounds__(256) void finalize_kernel(
        const int* __restrict__ inc, const int* __restrict__ bsum,
        int* __restrict__ rowstart, int* __restrict__ cursor) {
    int i = blockIdx.x * 256 + threadIdx.x;
    if (i >= N_NODES) return;
    int v = inc[i] + bsum[i >> 10];
    rowstart[i + 1] = v;
    if (i + 1 < N_NODES) cursor[i + 1] = v;
    if (i == 0) { rowstart[0] = 0; cursor[0] = 0; }
}

__global__ __launch_bounds__(256) void scatter_kernel(
        const int* __restrict__ ei, int* __restrict__ cursor,
        int* __restrict__ col, int* __restrict__ row) {
    int e = blockIdx.x * 256 + threadIdx.x;
    if (e >= E_TOT) return;
    int sv, dv;
    if (e < N_EDGES) { sv = ei[e]; dv = ei[N_EDGES + e]; }
    else             { sv = dv = e - N_EDGES; }
    int pos = atomicAdd(&cursor[dv], 1);
    col[pos] = sv;
    row[pos] = dv;
}

// ====== Layer 1 GEMM fused with attention logits: h1b(bf16), al1, ar1 =======
__global__ __launch_bounds__(256) void gemm1_fused(
        const float* __restrict__ x, const float* __restrict__ W1,
        const float* __restrict__ a_src, const float* __restrict__ a_dst,
        unsigned short* __restrict__ h1b, float* __restrict__ al,
        float* __restrict__ ar) {
    __shared__ float xs[8][IN_CH];
    const int j  = threadIdx.x;            // output column 0..255, head j>>5
    const int n0 = blockIdx.x * 8;
    for (int i = threadIdx.x; i < 8 * IN_CH; i += 256) {
        int m = i >> 7, k = i & (IN_CH - 1);
        xs[m][k] = x[(size_t)(n0 + m) * IN_CH + k];
    }
    __syncthreads();
    float acc[8] = {0.f,0.f,0.f,0.f,0.f,0.f,0.f,0.f};
    for (int k = 0; k < IN_CH; ++k) {
        float w = W1[k * HC + j];
        #pragma unroll
        for (int m = 0; m < 8; ++m) acc[m] += xs[m][k] * w;
    }
    #pragma unroll
    for (int m = 0; m < 8; ++m)
        h1b[(size_t)(n0 + m) * HC + j] = f2bf(acc[m]);
    const float asj = a_src[j], adj = a_dst[j];
    #pragma unroll
    for (int m = 0; m < 8; ++m) {
        float s = acc[m] * asj, d = acc[m] * adj;
        #pragma unroll
        for (int o = 16; o; o >>= 1) {
            s += __shfl_down(s, o, 32);
            d += __shfl_down(d, o, 32);
        }
        if ((j & 31) == 0) {
            al[(n0 + m) * HEADS + (j >> 5)] = s;
            ar[(n0 + m) * HEADS + (j >> 5)] = d;
        }
    }
}

// ===== Edge-parallel exp(leaky(logit)) precompute, layer 1 (bf16 out) =======
__global__ __launch_bounds__(256) void edge_alpha1(
        const int* __restrict__ col, const int* __restrict__ row,
        const float* __restrict__ al, const float* __restrict__ ar,
        unsigned short* __restrict__ expv) {
    int pos = blockIdx.x * 256 + threadIdx.x;
    if (pos >= E_TOT) return;
    int s = col[pos], d = row[pos];
    const float4* As = (const float4*)&al[s * HEADS];
    const float4* Ad = (const float4*)&ar[d * HEADS];
    float4 a0 = As[0], a1 = As[1], r0 = Ad[0], r1 = Ad[1];
    uint4 o;
    o.x = pack2(lrexp(a0.x + r0.x), lrexp(a0.y + r0.y));
    o.y = pack2(lrexp(a0.z + r0.z), lrexp(a0.w + r0.w));
    o.z = pack2(lrexp(a1.x + r1.x), lrexp(a1.y + r1.y));
    o.w = pack2(lrexp(a1.z + r1.z), lrexp(a1.w + r1.w));
    *(uint4*)&expv[(size_t)pos * 8] = o;
}

// ===== Layer 1 aggregation: denom + gather + bias + ELU -> bf16 =============
// pass 2 software-pipelined 4-deep for memory-level parallelism
__global__ __launch_bounds__(256) void aggr1_csr(
        const int* __restrict__ rowstart, const int* __restrict__ col,
        const unsigned short* __restrict__ expv,
        const unsigned short* __restrict__ h1b, const float* __restrict__ b1,
        unsigned short* __restrict__ out1b) {
    const int lane = threadIdx.x & 63;
    const int d = blockIdx.x * 4 + (threadIdx.x >> 6);
    if (d >= N_NODES) return;
    const int beg = rowstart[d], end = rowstart[d + 1];

    // pass 1: denom per head; flattened coalesced read, lane on fixed head lane&7
    float denom = 0.f;
    for (int i = beg * 8 + lane; i < end * 8; i += 64)
        denom += bf2f(expv[i]);
    denom += __shfl_xor(denom, 8, 64);
    denom += __shfl_xor(denom, 16, 64);
    denom += __shfl_xor(denom, 32, 64);
    const int h = lane >> 3;                     // head of my 4 channels
    const float inv = 1.f / (__shfl(denom, h, 64) + 1e-16f);

    // pass 2: weighted accumulation, 4 gathers in flight
    float4 acc = {0.f, 0.f, 0.f, 0.f};
    int i = beg;
    for (; i + 3 < end; i += 4) {
        const int s0 = col[i], s1 = col[i + 1], s2 = col[i + 2], s3 = col[i + 3];
        const float w0 = bf2f(expv[(i    ) * 8 + h]) * inv;
        const float w1 = bf2f(expv[(i + 1) * 8 + h]) * inv;
        const float w2 = bf2f(expv[(i + 2) * 8 + h]) * inv;
        const float w3 = bf2f(expv[(i + 3) * 8 + h]) * inv;
        const ushort4 v0 = *(const ushort4*)&h1b[(size_t)s0 * HC + 4 * lane];
        const ushort4 v1 = *(const ushort4*)&h1b[(size_t)s1 * HC + 4 * lane];
        const ushort4 v2 = *(const ushort4*)&h1b[(size_t)s2 * HC + 4 * lane];
        const ushort4 v3 = *(const ushort4*)&h1b[(size_t)s3 * HC + 4 * lane];
        acc.x += w0 * bf2f(v0.x); acc.y += w0 * bf2f(v0.y);
        acc.z += w0 * bf2f(v0.z); acc.w += w0 * bf2f(v0.w);
        acc.x += w1 * bf2f(v1.x); acc.y += w1 * bf2f(v1.y);
        acc.z += w1 * bf2f(v1.z); acc.w += w1 * bf2f(v1.w);
        acc.x += w2 * bf2f(v2.x); acc.y += w2 * bf2f(v2.y);
        acc.z += w2 * bf2f(v2.z); acc.w += w2 * bf2f(v2.w);
        acc.x += w3 * bf2f(v3.x); acc.y += w3 * bf2f(v3.y);
        acc.z += w3 * bf2f(v3.z); acc.w += w3 * bf2f(v3.w);
    }
    for (; i < end; ++i) {
        const int s = col[i];
        const float w = bf2f(expv[i * 8 + h]) * inv;
        const ushort4 hv = *(const ushort4*)&h1b[(size_t)s * HC + 4 * lane];
        acc.x += w * bf2f(hv.x); acc.y += w * bf2f(hv.y);
        acc.z += w * bf2f(hv.z); acc.w += w * bf2f(hv.w);
    }
    const float4 bb = *(const float4*)&b1[4 * lane];
    acc.x += bb.x; acc.y += bb.y; acc.z += bb.z; acc.w += bb.w;
    acc.x = acc.x > 0.f ? acc.x : expf(acc.x) - 1.f;
    acc.y = acc.y > 0.f ? acc.y : expf(acc.y) - 1.f;
    acc.z = acc.z > 0.f ? acc.z : expf(acc.z) - 1.f;
    acc.w = acc.w > 0.f ? acc.w : expf(acc.w) - 1.f;
    ushort4 ov = { f2bf(acc.x), f2bf(acc.y), f2bf(acc.z), f2bf(acc.w) };
    *(ushort4*)&out1b[(size_t)d * HC + 4 * lane] = ov;
}

// ====== Layer 2 GEMM fused with logits: h2b(bf16), al2, ar2 =================
__global__ __launch_bounds__(256) void gemm2_fused(
        const unsigned short* __restrict__ hinb, const float* __restrict__ W2,
        const float* __restrict__ a_src, const float* __restrict__ a_dst,
        unsigned short* __restrict__ h2b, float* __restrict__ al,
        float* __restrict__ ar) {
    __shared__ float xs[16][HC];
    const int j    = threadIdx.x & 63;
    const int msub = threadIdx.x >> 6;
    const int n0   = blockIdx.x * 16;
    for (int i = threadIdx.x; i < 16 * HC; i += 256) {
        int m = i >> 8, k = i & (HC - 1);
        xs[m][k] = bf2f(hinb[(size_t)(n0 + m) * HC + k]);
    }
    __syncthreads();
    float acc[4] = {0.f,0.f,0.f,0.f};
    for (int k = 0; k < HC; ++k) {
        float w = W2[k * OUTC + j];
        #pragma unroll
        for (int r = 0; r < 4; ++r) acc[r] += xs[msub + 4 * r][k] * w;
    }
    const float asj = a_src[j], adj = a_dst[j];
    #pragma unroll
    for (int r = 0; r < 4; ++r) {
        int n = n0 + msub + 4 * r;
        h2b[(size_t)n * OUTC + j] = f2bf(acc[r]);
        float s = acc[r] * asj, d = acc[r] * adj;
        #pragma unroll
        for (int o = 32; o; o >>= 1) {
            s += __shfl_down(s, o, 64);
            d += __shfl_down(d, o, 64);
        }
        if (j == 0) { al[n] = s; ar[n] = d; }
    }
}

// ===== Edge-parallel exp precompute, layer 2 (fp32 out) =====================
__global__ __launch_bounds__(256) void edge_alpha2(
        const int* __restrict__ col, const int* __restrict__ row,
        const float* __restrict__ al, const float* __restrict__ ar,
        float* __restrict__ expv) {
    int pos = blockIdx.x * 256 + threadIdx.x;
    if (pos >= E_TOT) return;
    expv[pos] = lrexp(al[col[pos]] + ar[row[pos]]);
}

// ===== Layer 2 aggregation: denom + gather + bias (fp32 out) ================
__global__ __launch_bounds__(256) void aggr2_csr(
        const int* __restrict__ rowstart, const int* __restrict__ col,
        const float* __restrict__ expv,
        const unsigned short* __restrict__ h2b, const float* __restrict__ b2,
        float* __restrict__ out) {
    const int lane = threadIdx.x & 63;
    const int d = blockIdx.x * 4 + (threadIdx.x >> 6);
    if (d >= N_NODES) return;
    const int beg = rowstart[d], end = rowstart[d + 1];

    float denom = 0.f;
    for (int i = beg + lane; i < end; i += 64)
        denom += expv[i];
    #pragma unroll
    for (int o = 1; o < 64; o <<= 1) denom += __shfl_xor(denom, o, 64);
    const float inv = 1.f / (denom + 1e-16f);

    float acc = 0.f;
    int i = beg;
    for (; i + 3 < end; i += 4) {
        const int s0 = col[i], s1 = col[i + 1], s2 = col[i + 2], s3 = col[i + 3];
        const float w0 = expv[i] * inv,     w1 = expv[i + 1] * inv;
        const float w2 = expv[i + 2] * inv, w3 = expv[i + 3] * inv;
        const unsigned short v0 = h2b[(size_t)s0 * OUTC + lane];
        const unsigned short v1 = h2b[(size_t)s1 * OUTC + lane];
        const unsigned short v2 = h2b[(size_t)s2 * OUTC + lane];
        const unsigned short v3 = h2b[(size_t)s3 * OUTC + lane];
        acc += w0 * bf2f(v0) + w1 * bf2f(v1) + w2 * bf2f(v2) + w3 * bf2f(v3);
    }
    for (; i < end; ++i)
        acc += expv[i] * inv * bf2f(h2b[(size_t)col[i] * OUTC + lane]);
    out[(size_t)d * OUTC + lane] = acc + b2[lane];
}

extern "C" void kernel_launch(void* const* d_in, const int* in_sizes, int n_in,
                              void* d_out, int out_size, void* d_ws, size_t ws_size,
                              hipStream_t stream) {
    const float* x      = (const float*)d_in[0];
    const int*   ei     = (const int*)  d_in[1];
    const float* W1     = (const float*)d_in[2];
    const float* a_src1 = (const float*)d_in[3];
    const float* a_dst1 = (const float*)d_in[4];
    const float* b1     = (const float*)d_in[5];
    const float* W2     = (const float*)d_in[6];
    const float* a_src2 = (const float*)d_in[7];
    const float* a_dst2 = (const float*)d_in[8];
    const float* b2     = (const float*)d_in[9];
    float* out = (float*)d_out;

    // ---- workspace layout ----
    char* p = (char*)d_ws;
    unsigned short* h1b   = (unsigned short*)p; p += (size_t)N_NODES * HC * 2;   // 25.6 MB
    unsigned short* out1b = (unsigned short*)p; p += (size_t)N_NODES * HC * 2;   // 25.6 MB
    unsigned short* h2b   = (unsigned short*)p; p += (size_t)N_NODES * OUTC * 2; // 6.4 MB
    unsigned short* expv1 = (unsigned short*)p; p += (size_t)E_TOT * 8 * 2;      // 13.6 MB
    float* expv2 = (float*)p; p += (size_t)E_TOT * sizeof(float);                // 3.4 MB
    float* al1  = (float*)p;  p += (size_t)N_NODES * HEADS * sizeof(float);
    float* ar1  = (float*)p;  p += (size_t)N_NODES * HEADS * sizeof(float);
    float* al2  = (float*)p;  p += (size_t)N_NODES * sizeof(float);
    float* ar2  = (float*)p;  p += (size_t)N_NODES * sizeof(float);
    int* deg      = (int*)p;  p += (size_t)N_NODES * sizeof(int);
    int* inc      = (int*)p;  p += (size_t)N_NODES * sizeof(int);
    int* bsum     = (int*)p;  p += (size_t)NSCAN_BLOCKS * sizeof(int);
    int* rowstart = (int*)p;  p += (size_t)(N_NODES + 1) * sizeof(int);
    int* cursor   = (int*)p;  p += (size_t)N_NODES * sizeof(int);
    int* col      = (int*)p;  p += (size_t)E_TOT * sizeof(int);
    int* row      = (int*)p;  p += (size_t)E_TOT * sizeof(int);

    // ---- CSR build ----
    hipMemsetAsync(deg, 0, (size_t)N_NODES * sizeof(int), stream);
    hist_kernel    <<<(E_TOT + 255)/256, 256, 0, stream>>>(ei, deg);
    scan1_kernel   <<<NSCAN_BLOCKS, 1024, 0, stream>>>(deg, inc, bsum);
    scan2_kernel   <<<1, 64, 0, stream>>>(bsum);
    finalize_kernel<<<(N_NODES + 255)/256, 256, 0, stream>>>(inc, bsum, rowstart, cursor);
    scatter_kernel <<<(E_TOT + 255)/256, 256, 0, stream>>>(ei, cursor, col, row);

    // ---- layer 1 ----
    gemm1_fused<<<N_NODES/8, 256, 0, stream>>>(x, W1, a_src1, a_dst1, h1b, al1, ar1);
    edge_alpha1<<<(E_TOT + 255)/256, 256, 0, stream>>>(col, row, al1, ar1, expv1);
    aggr1_csr  <<<(N_NODES + 3)/4, 256, 0, stream>>>(rowstart, col, expv1, h1b, b1, out1b);

    // ---- layer 2 ----
    gemm2_fused<<<N_NODES/16, 256, 0, stream>>>(out1b, W2, a_src2, a_dst2, h2b, al2, ar2);
    edge_alpha2<<<(E_TOT + 255)/256, 256, 0, stream>>>(col, row, al2, ar2, expv2);
    aggr2_csr  <<<(N_NODES + 3)/4, 256, 0, stream>>>(rowstart, col, expv2, h2b, b2, out);
}

// Round 6
// 271.191 us; speedup vs baseline: 5.3455x; 1.2783x over previous
//
#include <hip/hip_runtime.h>
#include <cstdint>

#define N_NODES 50000
#define N_EDGES 800000
#define E_TOT   (N_EDGES + N_NODES)   // 850000 with self-loops
#define IN_CH   128
#define HEADS   8
#define CCH     32
#define HC      256                    // HEADS*CCH
#define OUTC    64

typedef unsigned short ushort_t;
typedef __attribute__((ext_vector_type(8))) short bf16x8;
typedef __attribute__((ext_vector_type(4))) float f32x4;

// bf16 helpers (RNE rounding on pack)
static __device__ __forceinline__ unsigned short f2bf(float f) {
    unsigned u = __float_as_uint(f);
    u = u + 0x7fffu + ((u >> 16) & 1u);
    return (unsigned short)(u >> 16);
}
static __device__ __forceinline__ float bf2f(unsigned short h) {
    return __uint_as_float((unsigned)h << 16);
}
static __device__ __forceinline__ unsigned pack2(float lo, float hi) {
    return (unsigned)f2bf(lo) | ((unsigned)f2bf(hi) << 16);
}
static __device__ __forceinline__ float lrexp(float v) {
    v = v > 0.f ? v : 0.2f * v;        // LeakyReLU(0.2)
    return expf(v);
}
static __device__ __forceinline__ bf16x8 cvt8(float4 lo, float4 hi) {
    bf16x8 r;
    r[0] = (short)f2bf(lo.x); r[1] = (short)f2bf(lo.y);
    r[2] = (short)f2bf(lo.z); r[3] = (short)f2bf(lo.w);
    r[4] = (short)f2bf(hi.x); r[5] = (short)f2bf(hi.y);
    r[6] = (short)f2bf(hi.z); r[7] = (short)f2bf(hi.w);
    return r;
}

// ======================= CSR construction (per call) ========================
__global__ __launch_bounds__(256) void hist_kernel(
        const int* __restrict__ ei, int* __restrict__ deg) {
    int e = blockIdx.x * 256 + threadIdx.x;
    if (e >= E_TOT) return;
    int dv = (e < N_EDGES) ? ei[N_EDGES + e] : (e - N_EDGES);
    atomicAdd(&deg[dv], 1);
}

__global__ __launch_bounds__(1024) void scan1_kernel(
        const int* __restrict__ deg, int* __restrict__ inc, int* __restrict__ bsum) {
    __shared__ int sh[1024];
    const int tid = threadIdx.x;
    const int i = blockIdx.x * 1024 + tid;
    sh[tid] = (i < N_NODES) ? deg[i] : 0;
    __syncthreads();
    for (int o = 1; o < 1024; o <<= 1) {
        int t = (tid >= o) ? sh[tid - o] : 0;
        __syncthreads();
        sh[tid] += t;
        __syncthreads();
    }
    if (i < N_NODES) inc[i] = sh[tid];
    if (tid == 1023) bsum[blockIdx.x] = sh[1023];
}

#define NSCAN_BLOCKS ((N_NODES + 1023) / 1024)   // 49
__global__ void scan2_kernel(int* __restrict__ bsum) {
    if (threadIdx.x == 0 && blockIdx.x == 0) {
        int acc = 0;
        for (int k = 0; k < NSCAN_BLOCKS; ++k) { int t = bsum[k]; bsum[k] = acc; acc += t; }
    }
}

__global__ __launch_bounds__(256) void finalize_kernel(
        const int* __restrict__ inc, const int* __restrict__ bsum,
        int* __restrict__ rowstart, int* __restrict__ cursor) {
    int i = blockIdx.x * 256 + threadIdx.x;
    if (i >= N_NODES) return;
    int v = inc[i] + bsum[i >> 10];
    rowstart[i + 1] = v;
    if (i + 1 < N_NODES) cursor[i + 1] = v;
    if (i == 0) { rowstart[0] = 0; cursor[0] = 0; }
}

__global__ __launch_bounds__(256) void scatter_kernel(
        const int* __restrict__ ei, int* __restrict__ cursor,
        int* __restrict__ col, int* __restrict__ row) {
    int e = blockIdx.x * 256 + threadIdx.x;
    if (e >= E_TOT) return;
    int sv, dv;
    if (e < N_EDGES) { sv = ei[e]; dv = ei[N_EDGES + e]; }
    else             { sv = dv = e - N_EDGES; }
    int pos = atomicAdd(&cursor[dv], 1);
    col[pos] = sv;
    row[pos] = dv;
}

// ========== Repack W1,W2 to bf16 fragment-ordered tables ====================
// W1f[(nt*4+kk)*512 + lane*8 + j] = bf16(W1[(kk*32+(lane>>4)*8+j)*256 + nt*16+(lane&15)])
// W2f[(nt*8+kk)*512 + lane*8 + j] = bf16(W2[(kk*32+(lane>>4)*8+j)*64  + nt*16+(lane&15)])
__global__ __launch_bounds__(256) void repack_w(
        const float* __restrict__ W1, const float* __restrict__ W2,
        ushort_t* __restrict__ W1f, ushort_t* __restrict__ W2f) {
    int t = blockIdx.x * 256 + threadIdx.x;
    if (t < 32768) {
        int j = t & 7, lane = (t >> 3) & 63, f = t >> 9;
        int nt = f >> 2, kk = f & 3;
        int k = kk * 32 + (lane >> 4) * 8 + j;
        int n = nt * 16 + (lane & 15);
        W1f[t] = f2bf(W1[k * HC + n]);
    } else if (t < 32768 + 16384) {
        int u = t - 32768;
        int j = u & 7, lane = (u >> 3) & 63, f = u >> 9;
        int nt = f >> 3, kk = f & 7;
        int k = kk * 32 + (lane >> 4) * 8 + j;
        int n = nt * 16 + (lane & 15);
        W2f[u] = f2bf(W2[k * OUTC + n]);
    }
}

// ====== Layer 1 MFMA GEMM + fused logits: h1b(bf16), al1, ar1 ===============
// wave = 16 rows x 256 cols; block = 4 waves = 64 rows.
__global__ __launch_bounds__(256) void gemm1_mfma(
        const float* __restrict__ x, const ushort_t* __restrict__ W1f,
        const float* __restrict__ a_src, const float* __restrict__ a_dst,
        ushort_t* __restrict__ h1b, float* __restrict__ al, float* __restrict__ ar) {
    const int lane = threadIdx.x & 63;
    const int wv   = threadIdx.x >> 6;
    const int base = blockIdx.x * 64 + wv * 16;
    if (base >= N_NODES) return;
    const int am = base + (lane & 15);
    const int rm = am < N_NODES ? am : N_NODES - 1;

    // A fragments: rows of x, fp32 -> bf16 in-register
    bf16x8 a[4];
    const float* xr = &x[(size_t)rm * IN_CH + (lane >> 4) * 8];
    #pragma unroll
    for (int kk = 0; kk < 4; ++kk) {
        float4 lo = *(const float4*)&xr[kk * 32];
        float4 hi = *(const float4*)&xr[kk * 32 + 4];
        a[kk] = cvt8(lo, hi);
    }

    f32x4 acc[16];
    #pragma unroll
    for (int nt = 0; nt < 16; ++nt) acc[nt] = (f32x4){0.f, 0.f, 0.f, 0.f};

    const bf16x8* bp = (const bf16x8*)W1f;
    #pragma unroll
    for (int nt = 0; nt < 16; ++nt) {
        #pragma unroll
        for (int kk = 0; kk < 4; ++kk)
            acc[nt] = __builtin_amdgcn_mfma_f32_16x16x32_bf16(
                a[kk], bp[(nt * 4 + kk) * 64 + lane], acc[nt], 0, 0, 0);
    }

    // store h1b: C layout col=lane&15, row=(lane>>4)*4+r
    #pragma unroll
    for (int r = 0; r < 4; ++r) {
        int node = base + (lane >> 4) * 4 + r;
        if (node < N_NODES) {
            size_t off = (size_t)node * HC + (lane & 15);
            #pragma unroll
            for (int nt = 0; nt < 16; ++nt)
                h1b[off + nt * 16] = f2bf(acc[nt][r]);
        }
    }

    // fused logits: head h = tiles 2h,2h+1; reduce over lanes 0..15 group
    float asv[16], adv[16];
    #pragma unroll
    for (int nt = 0; nt < 16; ++nt) {
        asv[nt] = a_src[nt * 16 + (lane & 15)];
        adv[nt] = a_dst[nt * 16 + (lane & 15)];
    }
    #pragma unroll
    for (int h = 0; h < HEADS; ++h) {
        #pragma unroll
        for (int r = 0; r < 4; ++r) {
            float s = acc[2 * h][r] * asv[2 * h] + acc[2 * h + 1][r] * asv[2 * h + 1];
            float d = acc[2 * h][r] * adv[2 * h] + acc[2 * h + 1][r] * adv[2 * h + 1];
            s += __shfl_xor(s, 1, 64); s += __shfl_xor(s, 2, 64);
            s += __shfl_xor(s, 4, 64); s += __shfl_xor(s, 8, 64);
            d += __shfl_xor(d, 1, 64); d += __shfl_xor(d, 2, 64);
            d += __shfl_xor(d, 4, 64); d += __shfl_xor(d, 8, 64);
            int node = base + (lane >> 4) * 4 + r;
            if ((lane & 15) == 0 && node < N_NODES) {
                al[node * HEADS + h] = s;
                ar[node * HEADS + h] = d;
            }
        }
    }
}

// ===== Edge-parallel exp(leaky(logit)) precompute, layer 1 (bf16 out) =======
__global__ __launch_bounds__(256) void edge_alpha1(
        const int* __restrict__ col, const int* __restrict__ row,
        const float* __restrict__ al, const float* __restrict__ ar,
        unsigned short* __restrict__ expv) {
    int pos = blockIdx.x * 256 + threadIdx.x;
    if (pos >= E_TOT) return;
    int s = col[pos], d = row[pos];
    const float4* As = (const float4*)&al[s * HEADS];
    const float4* Ad = (const float4*)&ar[d * HEADS];
    float4 a0 = As[0], a1 = As[1], r0 = Ad[0], r1 = Ad[1];
    uint4 o;
    o.x = pack2(lrexp(a0.x + r0.x), lrexp(a0.y + r0.y));
    o.y = pack2(lrexp(a0.z + r0.z), lrexp(a0.w + r0.w));
    o.z = pack2(lrexp(a1.x + r1.x), lrexp(a1.y + r1.y));
    o.w = pack2(lrexp(a1.z + r1.z), lrexp(a1.w + r1.w));
    *(uint4*)&expv[(size_t)pos * 8] = o;
}

// ===== Layer 1 aggregation: denom + gather + bias + ELU -> bf16 =============
__global__ __launch_bounds__(256) void aggr1_csr(
        const int* __restrict__ rowstart, const int* __restrict__ col,
        const unsigned short* __restrict__ expv,
        const unsigned short* __restrict__ h1b, const float* __restrict__ b1,
        unsigned short* __restrict__ out1b) {
    const int lane = threadIdx.x & 63;
    const int d = blockIdx.x * 4 + (threadIdx.x >> 6);
    if (d >= N_NODES) return;
    const int beg = rowstart[d], end = rowstart[d + 1];

    float denom = 0.f;
    for (int i = beg * 8 + lane; i < end * 8; i += 64)
        denom += bf2f(expv[i]);
    denom += __shfl_xor(denom, 8, 64);
    denom += __shfl_xor(denom, 16, 64);
    denom += __shfl_xor(denom, 32, 64);
    const int h = lane >> 3;
    const float inv = 1.f / (__shfl(denom, h, 64) + 1e-16f);

    float4 acc = {0.f, 0.f, 0.f, 0.f};
    int i = beg;
    for (; i + 3 < end; i += 4) {
        const int s0 = col[i], s1 = col[i + 1], s2 = col[i + 2], s3 = col[i + 3];
        const float w0 = bf2f(expv[(i    ) * 8 + h]) * inv;
        const float w1 = bf2f(expv[(i + 1) * 8 + h]) * inv;
        const float w2 = bf2f(expv[(i + 2) * 8 + h]) * inv;
        const float w3 = bf2f(expv[(i + 3) * 8 + h]) * inv;
        const ushort4 v0 = *(const ushort4*)&h1b[(size_t)s0 * HC + 4 * lane];
        const ushort4 v1 = *(const ushort4*)&h1b[(size_t)s1 * HC + 4 * lane];
        const ushort4 v2 = *(const ushort4*)&h1b[(size_t)s2 * HC + 4 * lane];
        const ushort4 v3 = *(const ushort4*)&h1b[(size_t)s3 * HC + 4 * lane];
        acc.x += w0 * bf2f(v0.x); acc.y += w0 * bf2f(v0.y);
        acc.z += w0 * bf2f(v0.z); acc.w += w0 * bf2f(v0.w);
        acc.x += w1 * bf2f(v1.x); acc.y += w1 * bf2f(v1.y);
        acc.z += w1 * bf2f(v1.z); acc.w += w1 * bf2f(v1.w);
        acc.x += w2 * bf2f(v2.x); acc.y += w2 * bf2f(v2.y);
        acc.z += w2 * bf2f(v2.z); acc.w += w2 * bf2f(v2.w);
        acc.x += w3 * bf2f(v3.x); acc.y += w3 * bf2f(v3.y);
        acc.z += w3 * bf2f(v3.z); acc.w += w3 * bf2f(v3.w);
    }
    for (; i < end; ++i) {
        const int s = col[i];
        const float w = bf2f(expv[i * 8 + h]) * inv;
        const ushort4 hv = *(const ushort4*)&h1b[(size_t)s * HC + 4 * lane];
        acc.x += w * bf2f(hv.x); acc.y += w * bf2f(hv.y);
        acc.z += w * bf2f(hv.z); acc.w += w * bf2f(hv.w);
    }
    const float4 bb = *(const float4*)&b1[4 * lane];
    acc.x += bb.x; acc.y += bb.y; acc.z += bb.z; acc.w += bb.w;
    acc.x = acc.x > 0.f ? acc.x : expf(acc.x) - 1.f;
    acc.y = acc.y > 0.f ? acc.y : expf(acc.y) - 1.f;
    acc.z = acc.z > 0.f ? acc.z : expf(acc.z) - 1.f;
    acc.w = acc.w > 0.f ? acc.w : expf(acc.w) - 1.f;
    ushort4 ov = { f2bf(acc.x), f2bf(acc.y), f2bf(acc.z), f2bf(acc.w) };
    *(ushort4*)&out1b[(size_t)d * HC + 4 * lane] = ov;
}

// ====== Layer 2 MFMA GEMM + fused logits: h2b(bf16), al2, ar2 ===============
// wave = 16 rows x 64 cols; block = 4 waves = 64 rows.
__global__ __launch_bounds__(256) void gemm2_mfma(
        const ushort_t* __restrict__ hinb, const ushort_t* __restrict__ W2f,
        const float* __restrict__ a_src, const float* __restrict__ a_dst,
        ushort_t* __restrict__ h2b, float* __restrict__ al, float* __restrict__ ar) {
    const int lane = threadIdx.x & 63;
    const int wv   = threadIdx.x >> 6;
    const int base = blockIdx.x * 64 + wv * 16;
    if (base >= N_NODES) return;
    const int am = base + (lane & 15);
    const int rm = am < N_NODES ? am : N_NODES - 1;

    bf16x8 a[8];
    const bf16x8* ap = (const bf16x8*)&hinb[(size_t)rm * HC];
    #pragma unroll
    for (int kk = 0; kk < 8; ++kk)
        a[kk] = ap[kk * 4 + (lane >> 4)];

    f32x4 acc[4];
    #pragma unroll
    for (int nt = 0; nt < 4; ++nt) acc[nt] = (f32x4){0.f, 0.f, 0.f, 0.f};

    const bf16x8* bp = (const bf16x8*)W2f;
    #pragma unroll
    for (int nt = 0; nt < 4; ++nt) {
        #pragma unroll
        for (int kk = 0; kk < 8; ++kk)
            acc[nt] = __builtin_amdgcn_mfma_f32_16x16x32_bf16(
                a[kk], bp[(nt * 8 + kk) * 64 + lane], acc[nt], 0, 0, 0);
    }

    #pragma unroll
    for (int r = 0; r < 4; ++r) {
        int node = base + (lane >> 4) * 4 + r;
        if (node < N_NODES) {
            size_t off = (size_t)node * OUTC + (lane & 15);
            #pragma unroll
            for (int nt = 0; nt < 4; ++nt)
                h2b[off + nt * 16] = f2bf(acc[nt][r]);
        }
    }

    float asv[4], adv[4];
    #pragma unroll
    for (int nt = 0; nt < 4; ++nt) {
        asv[nt] = a_src[nt * 16 + (lane & 15)];
        adv[nt] = a_dst[nt * 16 + (lane & 15)];
    }
    #pragma unroll
    for (int r = 0; r < 4; ++r) {
        float s = 0.f, d = 0.f;
        #pragma unroll
        for (int nt = 0; nt < 4; ++nt) {
            s += acc[nt][r] * asv[nt];
            d += acc[nt][r] * adv[nt];
        }
        s += __shfl_xor(s, 1, 64); s += __shfl_xor(s, 2, 64);
        s += __shfl_xor(s, 4, 64); s += __shfl_xor(s, 8, 64);
        d += __shfl_xor(d, 1, 64); d += __shfl_xor(d, 2, 64);
        d += __shfl_xor(d, 4, 64); d += __shfl_xor(d, 8, 64);
        int node = base + (lane >> 4) * 4 + r;
        if ((lane & 15) == 0 && node < N_NODES) { al[node] = s; ar[node] = d; }
    }
}

// ===== Edge-parallel exp precompute, layer 2 (fp32 out) =====================
__global__ __launch_bounds__(256) void edge_alpha2(
        const int* __restrict__ col, const int* __restrict__ row,
        const float* __restrict__ al, const float* __restrict__ ar,
        float* __restrict__ expv) {
    int pos = blockIdx.x * 256 + threadIdx.x;
    if (pos >= E_TOT) return;
    expv[pos] = lrexp(al[col[pos]] + ar[row[pos]]);
}

// ===== Layer 2 aggregation: denom + gather + bias (fp32 out) ================
__global__ __launch_bounds__(256) void aggr2_csr(
        const int* __restrict__ rowstart, const int* __restrict__ col,
        const float* __restrict__ expv,
        const unsigned short* __restrict__ h2b, const float* __restrict__ b2,
        float* __restrict__ out) {
    const int lane = threadIdx.x & 63;
    const int d = blockIdx.x * 4 + (threadIdx.x >> 6);
    if (d >= N_NODES) return;
    const int beg = rowstart[d], end = rowstart[d + 1];

    float denom = 0.f;
    for (int i = beg + lane; i < end; i += 64)
        denom += expv[i];
    #pragma unroll
    for (int o = 1; o < 64; o <<= 1) denom += __shfl_xor(denom, o, 64);
    const float inv = 1.f / (denom + 1e-16f);

    float acc = 0.f;
    int i = beg;
    for (; i + 3 < end; i += 4) {
        const int s0 = col[i], s1 = col[i + 1], s2 = col[i + 2], s3 = col[i + 3];
        const float w0 = expv[i] * inv,     w1 = expv[i + 1] * inv;
        const float w2 = expv[i + 2] * inv, w3 = expv[i + 3] * inv;
        const unsigned short v0 = h2b[(size_t)s0 * OUTC + lane];
        const unsigned short v1 = h2b[(size_t)s1 * OUTC + lane];
        const unsigned short v2 = h2b[(size_t)s2 * OUTC + lane];
        const unsigned short v3 = h2b[(size_t)s3 * OUTC + lane];
        acc += w0 * bf2f(v0) + w1 * bf2f(v1) + w2 * bf2f(v2) + w3 * bf2f(v3);
    }
    for (; i < end; ++i)
        acc += expv[i] * inv * bf2f(h2b[(size_t)col[i] * OUTC + lane]);
    out[(size_t)d * OUTC + lane] = acc + b2[lane];
}

extern "C" void kernel_launch(void* const* d_in, const int* in_sizes, int n_in,
                              void* d_out, int out_size, void* d_ws, size_t ws_size,
                              hipStream_t stream) {
    const float* x      = (const float*)d_in[0];
    const int*   ei     = (const int*)  d_in[1];
    const float* W1     = (const float*)d_in[2];
    const float* a_src1 = (const float*)d_in[3];
    const float* a_dst1 = (const float*)d_in[4];
    const float* b1     = (const float*)d_in[5];
    const float* W2     = (const float*)d_in[6];
    const float* a_src2 = (const float*)d_in[7];
    const float* a_dst2 = (const float*)d_in[8];
    const float* b2     = (const float*)d_in[9];
    float* out = (float*)d_out;

    // ---- workspace layout ----
    char* p = (char*)d_ws;
    ushort_t* h1b   = (ushort_t*)p; p += (size_t)N_NODES * HC * 2;   // 25.6 MB
    ushort_t* out1b = (ushort_t*)p; p += (size_t)N_NODES * HC * 2;   // 25.6 MB
    ushort_t* h2b   = (ushort_t*)p; p += (size_t)N_NODES * OUTC * 2; // 6.4 MB
    ushort_t* expv1 = (ushort_t*)p; p += (size_t)E_TOT * 8 * 2;      // 13.6 MB
    float* expv2 = (float*)p; p += (size_t)E_TOT * sizeof(float);    // 3.4 MB
    ushort_t* W1f  = (ushort_t*)p; p += 32768 * 2;                   // 64 KB
    ushort_t* W2f  = (ushort_t*)p; p += 16384 * 2;                   // 32 KB
    float* al1  = (float*)p;  p += (size_t)N_NODES * HEADS * sizeof(float);
    float* ar1  = (float*)p;  p += (size_t)N_NODES * HEADS * sizeof(float);
    float* al2  = (float*)p;  p += (size_t)N_NODES * sizeof(float);
    float* ar2  = (float*)p;  p += (size_t)N_NODES * sizeof(float);
    int* deg      = (int*)p;  p += (size_t)N_NODES * sizeof(int);
    int* inc      = (int*)p;  p += (size_t)N_NODES * sizeof(int);
    int* bsum     = (int*)p;  p += (size_t)NSCAN_BLOCKS * sizeof(int);
    int* rowstart = (int*)p;  p += (size_t)(N_NODES + 1) * sizeof(int);
    int* cursor   = (int*)p;  p += (size_t)N_NODES * sizeof(int);
    int* col      = (int*)p;  p += (size_t)E_TOT * sizeof(int);
    int* row      = (int*)p;  p += (size_t)E_TOT * sizeof(int);

    // ---- CSR build + weight repack ----
    hipMemsetAsync(deg, 0, (size_t)N_NODES * sizeof(int), stream);
    repack_w       <<<192, 256, 0, stream>>>(W1, W2, W1f, W2f);
    hist_kernel    <<<(E_TOT + 255)/256, 256, 0, stream>>>(ei, deg);
    scan1_kernel   <<<NSCAN_BLOCKS, 1024, 0, stream>>>(deg, inc, bsum);
    scan2_kernel   <<<1, 64, 0, stream>>>(bsum);
    finalize_kernel<<<(N_NODES + 255)/256, 256, 0, stream>>>(inc, bsum, rowstart, cursor);
    scatter_kernel <<<(E_TOT + 255)/256, 256, 0, stream>>>(ei, cursor, col, row);

    // ---- layer 1 ----
    gemm1_mfma <<<(N_NODES + 63)/64, 256, 0, stream>>>(x, W1f, a_src1, a_dst1, h1b, al1, ar1);
    edge_alpha1<<<(E_TOT + 255)/256, 256, 0, stream>>>(col, row, al1, ar1, expv1);
    aggr1_csr  <<<(N_NODES + 3)/4, 256, 0, stream>>>(rowstart, col, expv1, h1b, b1, out1b);

    // ---- layer 2 ----
    gemm2_mfma <<<(N_NODES + 63)/64, 256, 0, stream>>>(out1b, W2f, a_src2, a_dst2, h2b, al2, ar2);
    edge_alpha2<<<(E_TOT + 255)/256, 256, 0, stream>>>(col, row, al2, ar2, expv2);
    aggr2_csr  <<<(N_NODES + 3)/4, 256, 0, stream>>>(rowstart, col, expv2, h2b, b2, out);
}